// Round 10
// baseline (349.569 us; speedup 1.0000x reference)
//
#include <hip/hip_runtime.h>
#include <math.h>

#define N_NODES 64000
#define N_EDGES 1048576
#define NB 1000
#define NG 64
#define NOUT 64
#define FC_SPLIT 500      // 500 x 256 = 128000 K-rows
#define BK_CAP 18000      // per-graph edge bucket capacity (mean 16384, +12.7 sigma)

typedef __attribute__((ext_vector_type(8))) short bfrag;   // 8 bf16 = 4 VGPRs
typedef __attribute__((ext_vector_type(4))) float f32x4;
typedef __attribute__((ext_vector_type(2))) float f32x2;

__device__ inline float bf2f(unsigned short u) {
    union { unsigned int i; float f; } x; x.i = ((unsigned int)u) << 16; return x.f;
}
__device__ inline float bflo(unsigned int u) {
    union { unsigned int i; float f; } x; x.i = u << 16; return x.f;
}
__device__ inline float bfhi(unsigned int u) {
    union { unsigned int i; float f; } x; x.i = u & 0xffff0000u; return x.f;
}
__device__ inline f32x2 upk(unsigned int u) {
    f32x2 r; r.x = bflo(u); r.y = bfhi(u); return r;
}
__device__ inline unsigned short f2bf(float f) {   // round-to-nearest-even
    union { float f; unsigned int i; } x; x.f = f;
    return (unsigned short)((x.i + 0x7FFFu + ((x.i >> 16) & 1u)) >> 16);
}
// XOR swizzle for 64x256-short LDS tile (16B groups), bijective per row.
__device__ inline int swz(int row, int g) { return g ^ (row & 7) ^ (g >> 3); }

// ---------------- CSR build, graph-bucketed ----------------

__global__ __launch_bounds__(256) void k_bucket(const int* __restrict__ src,
                                                const int* __restrict__ dst,
                                                int* __restrict__ gcnt,
                                                unsigned int* __restrict__ bucket) {
    __shared__ int lcnt[64];
    __shared__ int lbase[64];
    __shared__ int lcur[64];
    int t = threadIdx.x;
    int e0 = blockIdx.x * 4096;
    if (t < 64) { lcnt[t] = 0; lcur[t] = 0; }
    __syncthreads();
    for (int i = t; i < 4096; i += 256) {
        int d = dst[e0 + i];
        int g = d / NB;
        atomicAdd(&lcnt[g], 1);
    }
    __syncthreads();
    if (t < 64) lbase[t] = atomicAdd(&gcnt[t], lcnt[t]);
    __syncthreads();
    for (int i = t; i < 4096; i += 256) {
        int d = dst[e0 + i];
        int s = src[e0 + i];
        int g = d / NB;
        int pos = atomicAdd(&lcur[g], 1);
        unsigned int packed = ((unsigned int)(d - g * NB) << 10) | (unsigned int)(s - g * NB);
        bucket[(size_t)g * BK_CAP + lbase[g] + pos] = packed;
    }
}

__global__ __launch_bounds__(1024) void k_build(const int* __restrict__ gcnt,
                                                const unsigned int* __restrict__ bucket,
                                                int* __restrict__ rowptr,
                                                int* __restrict__ rowend,
                                                float* __restrict__ dinv,
                                                unsigned short* __restrict__ colp) {
    __shared__ int ind[1024];
    __shared__ int tmp[1024];
    int t = threadIdx.x;
    int g = blockIdx.x;
    int cnt = gcnt[g];
    size_t base = (size_t)g * BK_CAP;
    ind[t] = 0;
    __syncthreads();
    for (int i = t; i < cnt; i += 1024) {
        unsigned int p = bucket[base + i];
        atomicAdd(&ind[p >> 10], 1);
    }
    __syncthreads();
    int deg = ind[t];
    if (t < NB) dinv[g * NB + t] = rsqrtf((float)(deg + 1));
    tmp[t] = deg;
    __syncthreads();
    for (int off = 1; off < 1024; off <<= 1) {
        int o = (t >= off) ? tmp[t - off] : 0;
        __syncthreads();
        tmp[t] += o;
        __syncthreads();
    }
    int excl = tmp[t] - deg;
    if (t < NB) {
        rowptr[g * NB + t] = (int)base + excl;
        rowend[g * NB + t] = (int)base + excl + deg;
    }
    ind[t] = excl;           // reuse as cursor
    __syncthreads();
    for (int i = t; i < cnt; i += 1024) {
        unsigned int p = bucket[base + i];
        int dl = p >> 10;
        int pos = atomicAdd(&ind[dl], 1);
        colp[base + pos] = (unsigned short)(p & 1023u);
    }
}

// ---------------- casts ----------------

__global__ void k_cast_scale(const float* __restrict__ in, const float* __restrict__ dinv,
                             unsigned short* __restrict__ out) {
    int i = (blockIdx.x * blockDim.x + threadIdx.x) * 4;
    float d = dinv[i >> 7];
    float4 v = *(const float4*)(in + i);
    union { unsigned short s[4]; uint2 u; } o;
    o.s[0] = f2bf(v.x * d); o.s[1] = f2bf(v.y * d);
    o.s[2] = f2bf(v.z * d); o.s[3] = f2bf(v.w * d);
    *(uint2*)(out + i) = o.u;
}

// W[K][N] fp32 -> Wt[N][K] bf16
__global__ void k_wt(const float* __restrict__ W, unsigned short* __restrict__ Wt,
                     int K, int N) {
    int i = blockIdx.x * 256 + threadIdx.x;
    if (i < K * N) {
        int n = i / K, k = i % K;
        Wt[i] = f2bf(W[k * N + n]);
    }
}

// ---------------- pull aggregation (bf16 in / bf16 out, fp32 math) ----------------
// readlane (uniform) -> scalar neighbor base; x16 batched independent gathers.

template <int H, bool TANH>
__global__ void k_agg(const unsigned short* __restrict__ hs, unsigned short* __restrict__ op,
                      const int* __restrict__ rowptr, const int* __restrict__ rowend,
                      const unsigned short* __restrict__ col,
                      const float* __restrict__ dinv, const float* __restrict__ bias) {
    constexpr int VEC = H / 64;
    int lane = threadIdx.x & 63;
    int b = blockIdx.x;
    int c = b & 7;
    int j = b >> 3;
    int g = c + 8 * (j / 250);
    int chunk = j % 250;
    int v = g * NB + chunk * 4 + (threadIdx.x >> 6);
    const unsigned short* gb = hs + (size_t)g * NB * H;
    f32x2 a0, a1;
    {
        const unsigned short* r = hs + (size_t)v * H + lane * VEC;
        if (VEC == 2) {
            a0 = upk(*(const unsigned int*)r);
        } else {
            uint2 u = *(const uint2*)r;
            a0 = upk(u.x); a1 = upk(u.y);
        }
    }
    int beg = rowptr[v], end = rowend[v];
    for (int e0 = beg; e0 < end; e0 += 64) {
        int me = e0 + lane;
        int s = (me < end) ? (int)col[me] : 0;
        int cnt = min(64, end - e0);
        int i = 0;
        for (; i + 16 <= cnt; i += 16) {
            int sx[16];
#pragma unroll
            for (int q = 0; q < 16; ++q) sx[q] = __builtin_amdgcn_readlane(s, i + q);
            if (VEC == 2) {
                unsigned int u[16];
#pragma unroll
                for (int q = 0; q < 16; ++q)
                    u[q] = *(const unsigned int*)(gb + (size_t)sx[q] * H + lane * 2);
#pragma unroll
                for (int q = 0; q < 16; ++q) a0 += upk(u[q]);
            } else {
                uint2 u[16];
#pragma unroll
                for (int q = 0; q < 16; ++q)
                    u[q] = *(const uint2*)(gb + (size_t)sx[q] * H + lane * 4);
#pragma unroll
                for (int q = 0; q < 16; ++q) { a0 += upk(u[q].x); a1 += upk(u[q].y); }
            }
        }
        for (; i + 8 <= cnt; i += 8) {
            int sx[8];
#pragma unroll
            for (int q = 0; q < 8; ++q) sx[q] = __builtin_amdgcn_readlane(s, i + q);
            if (VEC == 2) {
                unsigned int u[8];
#pragma unroll
                for (int q = 0; q < 8; ++q)
                    u[q] = *(const unsigned int*)(gb + (size_t)sx[q] * H + lane * 2);
#pragma unroll
                for (int q = 0; q < 8; ++q) a0 += upk(u[q]);
            } else {
                uint2 u[8];
#pragma unroll
                for (int q = 0; q < 8; ++q)
                    u[q] = *(const uint2*)(gb + (size_t)sx[q] * H + lane * 4);
#pragma unroll
                for (int q = 0; q < 8; ++q) { a0 += upk(u[q].x); a1 += upk(u[q].y); }
            }
        }
        for (; i + 4 <= cnt; i += 4) {
            int sx[4];
#pragma unroll
            for (int q = 0; q < 4; ++q) sx[q] = __builtin_amdgcn_readlane(s, i + q);
            if (VEC == 2) {
                unsigned int u[4];
#pragma unroll
                for (int q = 0; q < 4; ++q)
                    u[q] = *(const unsigned int*)(gb + (size_t)sx[q] * H + lane * 2);
#pragma unroll
                for (int q = 0; q < 4; ++q) a0 += upk(u[q]);
            } else {
                uint2 u[4];
#pragma unroll
                for (int q = 0; q < 4; ++q)
                    u[q] = *(const uint2*)(gb + (size_t)sx[q] * H + lane * 4);
#pragma unroll
                for (int q = 0; q < 4; ++q) { a0 += upk(u[q].x); a1 += upk(u[q].y); }
            }
        }
        for (; i < cnt; ++i) {
            int ss = __builtin_amdgcn_readlane(s, i);
            if (VEC == 2) {
                a0 += upk(*(const unsigned int*)(gb + (size_t)ss * H + lane * 2));
            } else {
                uint2 u = *(const uint2*)(gb + (size_t)ss * H + lane * 4);
                a0 += upk(u.x); a1 += upk(u.y);
            }
        }
    }
    float dv = dinv[v];
    float acc[4];
    acc[0] = a0.x; acc[1] = a0.y;
    if (VEC == 4) { acc[2] = a1.x; acc[3] = a1.y; }
    if (TANH) {
#pragma unroll
        for (int q = 0; q < VEC; ++q) acc[q] = tanhf(acc[q] * dv + bias[lane * VEC + q]);
    } else {
#pragma unroll
        for (int q = 0; q < VEC; ++q) acc[q] *= dv;
    }
    unsigned short* o = op + (size_t)v * H + lane * VEC;
    if (VEC == 2) {
        union { unsigned short s[2]; unsigned int u; } pk;
        pk.s[0] = f2bf(acc[0]); pk.s[1] = f2bf(acc[1]);
        *(unsigned int*)o = pk.u;
    } else {
        union { unsigned short s[4]; uint2 u; } pk;
        pk.s[0] = f2bf(acc[0]); pk.s[1] = f2bf(acc[1]);
        pk.s[2] = f2bf(acc[2]); pk.s[3] = f2bf(acc[3]);
        *(uint2*)o = pk.u;
    }
}

// ---------------- layer-1 GEMM: C[64000,256] = tanh(A[64000,128] @ W1 + b1) * dinv
// ALL 16 B-frags loaded in one burst (single latency exposure), A via LDS.

__global__ __launch_bounds__(256) void k_gemm1(const unsigned short* __restrict__ A,
                                               const unsigned short* __restrict__ W1t,
                                               const float* __restrict__ b1,
                                               const float* __restrict__ dinv,
                                               unsigned short* __restrict__ C) {
    constexpr int K = 128, N = 256;
    __shared__ unsigned short at[64 * 136];
    int t = threadIdx.x;
    int w = t >> 6, l = t & 63;
    int lm = l & 15, lq = l >> 4;
    int m0 = blockIdx.x * 64;
    int n0 = w * 64;
    {   // stage A: thread t -> row t>>2, 32-short chunk (t&3)*32
        int row = t >> 2, kc = (t & 3) * 32;
        const unsigned short* gr = A + (size_t)(m0 + row) * K + kc;
        unsigned short* lr = at + row * 136 + kc;
        uint4 v0 = *(const uint4*)(gr);
        uint4 v1 = *(const uint4*)(gr + 8);
        uint4 v2 = *(const uint4*)(gr + 16);
        uint4 v3 = *(const uint4*)(gr + 24);
        *(uint4*)(lr) = v0; *(uint4*)(lr + 8) = v1;
        *(uint4*)(lr + 16) = v2; *(uint4*)(lr + 24) = v3;
    }
    const unsigned short* Bb = W1t + (size_t)(n0 + lm) * K + lq * 8;
    bfrag bfb[16];   // [it*4+j], all of this wave's W1 slice: one burst
#pragma unroll
    for (int it = 0; it < 4; ++it)
#pragma unroll
        for (int j = 0; j < 4; ++j)
            bfb[it * 4 + j] = *(const bfrag*)(Bb + (size_t)j * 16 * K + it * 32);
    __syncthreads();
    f32x4 acc[4][4] = {};
#pragma unroll
    for (int it = 0; it < 4; ++it) {
        int ks = it * 32;
        bfrag af[4];
#pragma unroll
        for (int i = 0; i < 4; ++i) af[i] = *(const bfrag*)&at[(i * 16 + lm) * 136 + ks + lq * 8];
#pragma unroll
        for (int i = 0; i < 4; ++i)
#pragma unroll
            for (int j = 0; j < 4; ++j)
                acc[i][j] = __builtin_amdgcn_mfma_f32_16x16x32_bf16(af[i], bfb[it * 4 + j], acc[i][j], 0, 0, 0);
    }
    float bj[4];
#pragma unroll
    for (int j = 0; j < 4; ++j) bj[j] = b1[n0 + j * 16 + lm];
    int row0 = lq * 4;
    float drow[4][4];
#pragma unroll
    for (int i = 0; i < 4; ++i)
#pragma unroll
        for (int r = 0; r < 4; ++r) drow[i][r] = dinv[m0 + i * 16 + row0 + r];
#pragma unroll
    for (int i = 0; i < 4; ++i)
#pragma unroll
        for (int j = 0; j < 4; ++j)
#pragma unroll
            for (int r = 0; r < 4; ++r) {
                float v = tanhf(acc[i][j][r] + bj[j]) * drow[i][r];
                C[(size_t)(m0 + i * 16 + row0 + r) * N + n0 + j * 16 + lm] = f2bf(v);
            }
}

// ---------------- fused layers 2+3 GEMM:
// XOR-swizzled 32KB LDS A-tile. Stage1: two half-K chunks, each = 16 B-frags in
// one burst + 64 MFMAs (2 latency exposures instead of 8). Stage2: all 16 B-frags
// upfront. C2 round-trips through the same LDS buffer.

__global__ __launch_bounds__(256) void k_gemm23(const unsigned short* __restrict__ A,
                                                const unsigned short* __restrict__ W2t,
                                                const float* __restrict__ b2,
                                                const unsigned short* __restrict__ W3t,
                                                const float* __restrict__ dinv,
                                                unsigned short* __restrict__ C) {
    constexpr int K = 256, N3 = 128;
    __shared__ unsigned short at[64 * 256];   // 32768 B, swizzled; A-tile then C2
    int t = threadIdx.x;
    int w = t >> 6, l = t & 63;
    int lm = l & 15, lq = l >> 4;
    int m0 = blockIdx.x * 64;
    int n0 = w * 64;
    int row0 = lq * 4;
    {   // stage A
        int row = t >> 2, c = t & 3;
        const unsigned short* gr = A + (size_t)(m0 + row) * K + c * 64;
        unsigned short* lr = at + row * 256;
        uint4 v[8];
#pragma unroll
        for (int j = 0; j < 8; ++j) v[j] = *(const uint4*)(gr + j * 8);
#pragma unroll
        for (int j = 0; j < 8; ++j) {
            int gidx = c * 8 + j;
            *(uint4*)(lr + swz(row, gidx) * 8) = v[j];
        }
    }
    __syncthreads();
    // ---- stage 1: C2 = tanh(A @ W2 + b2) ----
    f32x4 acc[4][4] = {};
    {
        const unsigned short* Bb = W2t + (size_t)(n0 + lm) * K + lq * 8;
#pragma unroll
        for (int half = 0; half < 2; ++half) {
            bfrag bfb[16];   // this half's 16 B-frags: one burst
#pragma unroll
            for (int it2 = 0; it2 < 4; ++it2)
#pragma unroll
                for (int j = 0; j < 4; ++j)
                    bfb[it2 * 4 + j] = *(const bfrag*)(Bb + (size_t)j * 16 * K + (half * 4 + it2) * 32);
#pragma unroll
            for (int it2 = 0; it2 < 4; ++it2) {
                int gidx = (half * 4 + it2) * 4 + lq;
                bfrag af[4];
#pragma unroll
                for (int i = 0; i < 4; ++i) {
                    int row = i * 16 + lm;
                    af[i] = *(const bfrag*)&at[row * 256 + swz(row, gidx) * 8];
                }
#pragma unroll
                for (int i = 0; i < 4; ++i)
#pragma unroll
                    for (int j = 0; j < 4; ++j)
                        acc[i][j] = __builtin_amdgcn_mfma_f32_16x16x32_bf16(af[i], bfb[it2 * 4 + j], acc[i][j], 0, 0, 0);
            }
        }
    }
    __syncthreads();   // all stage-1 A-reads done; safe to overwrite with C2
    {
        float bj[4];
#pragma unroll
        for (int j = 0; j < 4; ++j) bj[j] = b2[n0 + j * 16 + lm];
#pragma unroll
        for (int i = 0; i < 4; ++i)
#pragma unroll
            for (int j = 0; j < 4; ++j) {
                int colb = n0 + j * 16 + lm;
                int gidx = colb >> 3, off = colb & 7;
#pragma unroll
                for (int r = 0; r < 4; ++r) {
                    int row = i * 16 + row0 + r;
                    at[row * 256 + swz(row, gidx) * 8 + off] =
                        f2bf(tanhf(acc[i][j][r] + bj[j]));
                }
            }
    }
    __syncthreads();
    // ---- stage 2: C3 = (C2 @ W3) * dinv ----
    {
        int n3 = w * 32;
        const unsigned short* Bb = W3t + (size_t)(n3 + lm) * K + lq * 8;
        bfrag bfb[16];   // [it*2+j], all of this wave's W3 slice: one burst
#pragma unroll
        for (int it = 0; it < 8; ++it)
#pragma unroll
            for (int j = 0; j < 2; ++j)
                bfb[it * 2 + j] = *(const bfrag*)(Bb + (size_t)j * 16 * K + it * 32);
        f32x4 acc2[4][2] = {};
#pragma unroll
        for (int it = 0; it < 8; ++it) {
            int gidx = it * 4 + lq;
            bfrag af[4];
#pragma unroll
            for (int i = 0; i < 4; ++i) {
                int row = i * 16 + lm;
                af[i] = *(const bfrag*)&at[row * 256 + swz(row, gidx) * 8];
            }
#pragma unroll
            for (int i = 0; i < 4; ++i)
#pragma unroll
                for (int j = 0; j < 2; ++j)
                    acc2[i][j] = __builtin_amdgcn_mfma_f32_16x16x32_bf16(af[i], bfb[it * 2 + j], acc2[i][j], 0, 0, 0);
        }
        float drow[4][4];
#pragma unroll
        for (int i = 0; i < 4; ++i)
#pragma unroll
            for (int r = 0; r < 4; ++r) drow[i][r] = dinv[m0 + i * 16 + row0 + r];
#pragma unroll
        for (int i = 0; i < 4; ++i)
#pragma unroll
            for (int j = 0; j < 2; ++j)
#pragma unroll
                for (int r = 0; r < 4; ++r)
                    C[(size_t)(m0 + i * 16 + row0 + r) * N3 + n3 + j * 16 + lm] =
                        f2bf(acc2[i][j][r] * drow[i][r]);
    }
}

// ---------------- final FC: out[64,64] = h[64,128000](bf16) @ Wfc[128000,64](f32) + bfc

__global__ void k_fc(const unsigned short* __restrict__ A, const float* __restrict__ B,
                     float* __restrict__ part) {
    __shared__ float As[16][68];
    __shared__ float Bs[16][68];
    const int KROW = NB * 128;         // 128000
    int t = threadIdx.x;
    int tx = t & 15, ty = t >> 4;
    int k0b = blockIdx.x * 256;
    float acc[4][4] = {};
    for (int k0 = k0b; k0 < k0b + 256; k0 += 16) {
        int arow = t >> 2, ak = (t & 3) << 2;
        uint2 ua = *(const uint2*)(A + (size_t)arow * KROW + k0 + ak);
        As[ak + 0][arow] = bflo(ua.x);
        As[ak + 1][arow] = bfhi(ua.x);
        As[ak + 2][arow] = bflo(ua.y);
        As[ak + 3][arow] = bfhi(ua.y);
        int bk = t >> 4, bn4 = (t & 15) << 2;
        *(float4*)&Bs[bk][bn4] = *(const float4*)(B + (size_t)(k0 + bk) * NOUT + bn4);
        __syncthreads();
#pragma unroll
        for (int kk = 0; kk < 16; ++kk) {
            float4 a = *(const float4*)&As[kk][ty << 2];
            float4 b = *(const float4*)&Bs[kk][tx << 2];
            acc[0][0] += a.x * b.x; acc[0][1] += a.x * b.y; acc[0][2] += a.x * b.z; acc[0][3] += a.x * b.w;
            acc[1][0] += a.y * b.x; acc[1][1] += a.y * b.y; acc[1][2] += a.y * b.z; acc[1][3] += a.y * b.w;
            acc[2][0] += a.z * b.x; acc[2][1] += a.z * b.y; acc[2][2] += a.z * b.z; acc[2][3] += a.z * b.w;
            acc[3][0] += a.w * b.x; acc[3][1] += a.w * b.y; acc[3][2] += a.w * b.z; acc[3][3] += a.w * b.w;
        }
        __syncthreads();
    }
    float* po = part + (size_t)blockIdx.x * (NG * NOUT);
#pragma unroll
    for (int i = 0; i < 4; ++i) {
        float4 r;
        r.x = acc[i][0]; r.y = acc[i][1]; r.z = acc[i][2]; r.w = acc[i][3];
        *(float4*)&po[((ty << 2) + i) * NOUT + (tx << 2)] = r;
    }
}

__global__ void k_fc_reduce(const float* __restrict__ part, const float* __restrict__ bfc,
                            float* __restrict__ out) {
    int i = blockIdx.x * blockDim.x + threadIdx.x;   // 4096 threads
    float s = bfc[i & 63];
    for (int b = 0; b < FC_SPLIT; ++b) s += part[(size_t)b * (NG * NOUT) + i];
    out[i] = s;
}

// ---------------- driver ----------------

static inline size_t align256(size_t x) { return (x + 255) & ~(size_t)255; }

extern "C" void kernel_launch(void* const* d_in, const int* in_sizes, int n_in,
                              void* d_out, int out_size, void* d_ws, size_t ws_size,
                              hipStream_t stream) {
    const float* x   = (const float*)d_in[0];
    const int*   ei  = (const int*)d_in[1];
    const int*   src = ei;
    const int*   dst = ei + N_EDGES;
    const float* W1  = (const float*)d_in[3];
    const float* b1  = (const float*)d_in[4];
    const float* W2  = (const float*)d_in[5];
    const float* b2  = (const float*)d_in[6];
    const float* W3  = (const float*)d_in[7];
    const float* b3  = (const float*)d_in[8];
    const float* Wfc = (const float*)d_in[9];
    const float* bfc = (const float*)d_in[10];
    float* out = (float*)d_out;

    char* w = (char*)d_ws;
    unsigned short* P0 = (unsigned short*)w; w += align256((size_t)N_NODES * 256 * 2);
    unsigned short* P1 = (unsigned short*)w; w += align256((size_t)N_NODES * 256 * 2);
    unsigned short* P2 = (unsigned short*)w; w += align256((size_t)N_NODES * 256 * 2);
    int* rowptr = (int*)w;      w += align256((size_t)N_NODES * 4);
    int* rowend = (int*)w;      w += align256((size_t)N_NODES * 4);
    float* dinv = (float*)w;    w += align256((size_t)N_NODES * 4);
    int* gcnt = (int*)w;        w += align256((size_t)NG * 4);
    unsigned int* bucket = (unsigned int*)w; w += align256((size_t)NG * BK_CAP * 4);
    unsigned short* colp = (unsigned short*)w; w += align256((size_t)NG * BK_CAP * 2);
    float* fcpart = (float*)w;  w += align256((size_t)FC_SPLIT * NG * NOUT * 4);
    unsigned short* W1t = (unsigned short*)w; w += align256((size_t)128 * 256 * 2);
    unsigned short* W2t = (unsigned short*)w; w += align256((size_t)256 * 256 * 2);
    unsigned short* W3t = (unsigned short*)w; w += align256((size_t)256 * 128 * 2);

    // CSR build
    hipMemsetAsync(gcnt, 0, (size_t)NG * 4, stream);
    k_bucket<<<N_EDGES / 4096, 256, 0, stream>>>(src, dst, gcnt, bucket);
    k_build<<<NG, 1024, 0, stream>>>(gcnt, bucket, rowptr, rowend, dinv, colp);

    // casts
    k_cast_scale<<<(N_NODES * 128 / 4) / 256, 256, 0, stream>>>(x, dinv, P0);
    k_wt<<<(128 * 256 + 255) / 256, 256, 0, stream>>>(W1, W1t, 128, 256);
    k_wt<<<(256 * 256 + 255) / 256, 256, 0, stream>>>(W2, W2t, 256, 256);
    k_wt<<<(256 * 128 + 255) / 256, 256, 0, stream>>>(W3, W3t, 256, 128);

    // layer 1: agg(H=128), gemm1 (tanh+b1+prescale) -> P2 (H=256)
    k_agg<128, false><<<N_NODES / 4, 256, 0, stream>>>(P0, P1, rowptr, rowend, colp, dinv, nullptr);
    k_gemm1<<<N_NODES / 64, 256, 0, stream>>>(P1, W1t, b1, dinv, P2);

    // layer 2: agg(H=256) -> P0; fused gemm2+gemm3 -> P1 (H=128, prescaled)
    k_agg<256, false><<<N_NODES / 4, 256, 0, stream>>>(P2, P0, rowptr, rowend, colp, dinv, nullptr);
    k_gemm23<<<N_NODES / 64, 256, 0, stream>>>(P0, W2t, b2, W3t, dinv, P1);

    // layer 3 aggregation: agg(H=128) + b3 + tanh -> P0
    k_agg<128, true><<<N_NODES / 4, 256, 0, stream>>>(P1, P0, rowptr, rowend, colp, dinv, b3);

    // final FC
    k_fc<<<FC_SPLIT, 256, 0, stream>>>(P0, Wfc, fcpart);
    k_fc_reduce<<<NG * NOUT / 256, 256, 0, stream>>>(fcpart, bfc, out);
}